// Round 3
// baseline (643.539 us; speedup 1.0000x reference)
//
#include <hip/hip_runtime.h>

#define HBLK 128  // hidden width, fixed by problem

// ---------------- CSR build ----------------
__global__ void zero_counts(int* counts, int n) {
    int i = blockIdx.x * 256 + threadIdx.x;
    if (i < n) counts[i] = 0;
}

__global__ void hist_k(const int* __restrict__ dst, int* counts, int E) {
    int e = blockIdx.x * 256 + threadIdx.x;
    if (e < E) atomicAdd(&counts[dst[e]], 1);
}

// single-block exclusive scan over N counts -> offsets[N+1], cursor copy
__global__ void scan_k(const int* __restrict__ counts, int* offs, int* cursor, int n) {
    __shared__ int lds[256];
    const int t = threadIdx.x;
    const int CH = (n + 255) / 256;
    const int base = t * CH;
    int s = 0;
    for (int i = 0; i < CH; ++i) {
        int idx = base + i;
        if (idx < n) s += counts[idx];
    }
    lds[t] = s;
    __syncthreads();
    for (int off = 1; off < 256; off <<= 1) {
        int add = (t >= off) ? lds[t - off] : 0;
        __syncthreads();
        lds[t] += add;
        __syncthreads();
    }
    int run = lds[t] - s;  // exclusive prefix
    for (int i = 0; i < CH; ++i) {
        int idx = base + i;
        if (idx < n) {
            offs[idx] = run;
            cursor[idx] = run;
            run += counts[idx];
        }
    }
    if (t == 255) offs[n] = lds[255];
}

__global__ void fill_k(const int* __restrict__ dst, const int* __restrict__ src,
                       int* cursor, int* __restrict__ src_sorted, int E) {
    int e = blockIdx.x * 256 + threadIdx.x;
    if (e < E) {
        int p = atomicAdd(&cursor[dst[e]], 1);
        src_sorted[p] = src[e];
    }
}

// ---------------- fp32 GEMM, 64x128 C-tile, 8x8/thread, 128 threads ----------------
// C[M x 128] = act(([A1|A2]) @ B^T + bias); A1: K1 cols, A2: Ktot-K1 cols.
// gridDim.y selects (B1,C1) vs (B2,C2) for the dual Ws/Wf case.
// flags: 2 = relu. Ktot multiple of 4; M guarded.
__global__ __launch_bounds__(128, 2) void gemm_k(
    const float* __restrict__ A1, int lda1, int K1,
    const float* __restrict__ A2, int lda2, int Ktot,
    const float* __restrict__ B1, const float* __restrict__ B2, int ldb,
    const float* __restrict__ bias,
    float* __restrict__ C1, float* __restrict__ C2,
    int M, int flags)
{
    __shared__ float As[16][68];    // k-major, 64 rows + pad (272B rows, 16B aligned)
    __shared__ float Bs[16][132];   // k-major, 128 cols + pad (528B rows, 16B aligned)
    const float* __restrict__ B = (blockIdx.y == 0) ? B1 : B2;
    float* __restrict__ C = (blockIdx.y == 0) ? C1 : C2;
    const int tid = threadIdx.x;
    const int row0 = blockIdx.x * 64;
    const int cg = tid & 15;   // cols cg*8 .. cg*8+7
    const int rg = tid >> 4;   // rows rg*8 .. rg*8+7
    float acc[8][8] = {};

    for (int kb = 0; kb < Ktot; kb += 16) {
        // stage A: 64 rows x 16 k = 256 float4, 2 per thread
#pragma unroll
        for (int rep = 0; rep < 2; ++rep) {
            const int idx = tid + 128 * rep;
            const int r = idx >> 2, k4 = idx & 3;
            const int gr = row0 + r, gk = kb + k4 * 4;
            float4 v = make_float4(0.f, 0.f, 0.f, 0.f);
            if (gr < M && gk + 4 <= Ktot) {
                v = (gk < K1) ? *(const float4*)&A1[(long)gr * lda1 + gk]
                              : *(const float4*)&A2[(long)gr * lda2 + (gk - K1)];
            }
            As[k4 * 4 + 0][r] = v.x;
            As[k4 * 4 + 1][r] = v.y;
            As[k4 * 4 + 2][r] = v.z;
            As[k4 * 4 + 3][r] = v.w;
        }
        // stage B: 128 cols x 16 k = 512 float4, 4 per thread
#pragma unroll
        for (int rep = 0; rep < 4; ++rep) {
            const int idx = tid + 128 * rep;
            const int c = idx >> 2, k4 = idx & 3;
            const int gk = kb + k4 * 4;
            float4 v = make_float4(0.f, 0.f, 0.f, 0.f);
            if (gk + 4 <= Ktot) v = *(const float4*)&B[(long)c * ldb + gk];
            Bs[k4 * 4 + 0][c] = v.x;
            Bs[k4 * 4 + 1][c] = v.y;
            Bs[k4 * 4 + 2][c] = v.z;
            Bs[k4 * 4 + 3][c] = v.w;
        }
        __syncthreads();
#pragma unroll
        for (int kk = 0; kk < 16; ++kk) {
            float av[8], bv[8];
            *(float4*)&av[0] = *(const float4*)&As[kk][rg * 8];
            *(float4*)&av[4] = *(const float4*)&As[kk][rg * 8 + 4];
            *(float4*)&bv[0] = *(const float4*)&Bs[kk][cg * 8];
            *(float4*)&bv[4] = *(const float4*)&Bs[kk][cg * 8 + 4];
#pragma unroll
            for (int i = 0; i < 8; ++i)
#pragma unroll
                for (int j = 0; j < 8; ++j)
                    acc[i][j] += av[i] * bv[j];
        }
        __syncthreads();
    }

#pragma unroll
    for (int i = 0; i < 8; ++i) {
        const int gr = row0 + rg * 8 + i;
        if (gr >= M) continue;
#pragma unroll
        for (int j0 = 0; j0 < 8; j0 += 4) {
            float4 v;
            float* vp = (float*)&v;
#pragma unroll
            for (int j = 0; j < 4; ++j) {
                float x = acc[i][j0 + j] + (bias ? bias[cg * 8 + j0 + j] : 0.f);
                if (flags & 2) x = fmaxf(x, 0.f);
                vp[j] = x;
            }
            *(float4*)&C[(long)gr * HBLK + cg * 8 + j0] = v;
        }
    }
}

// ---------------- per-node attention-score halves: s_src = z@a[:128], s_dst = z@a[128:] ----------------
__global__ void compute_s(const float* __restrict__ z, const float* __restrict__ a,
                          float* __restrict__ s_src, float* __restrict__ s_dst, int N) {
    const int wave = threadIdx.x >> 6;
    const int lane = threadIdx.x & 63;
    const int n = blockIdx.x * 4 + wave;
    if (n >= N) return;
    const float* zr = z + (long)n * HBLK;
    float v0 = zr[lane], v1 = zr[lane + 64];
    float ss = v0 * a[lane] + v1 * a[lane + 64];
    float sd = v0 * a[128 + lane] + v1 * a[192 + lane];
#pragma unroll
    for (int off = 32; off > 0; off >>= 1) {
        ss += __shfl_down(ss, off);
        sd += __shfl_down(sd, off);
    }
    if (lane == 0) {
        s_src[n] = ss;
        s_dst[n] = sd;
    }
}

// ---------------- GAT edge softmax + aggregation; one block (128 thr) per dst node ----------------
__global__ void gat_agg(const float* __restrict__ h_in, const float* __restrict__ hs,
                        const float* __restrict__ z,
                        const float* __restrict__ s_src, const float* __restrict__ s_dst,
                        const int* __restrict__ offs, const int* __restrict__ src_sorted,
                        float* __restrict__ h_out) {
    const int n = blockIdx.x;
    const int t = threadIdx.x;  // 128
    const int beg = offs[n], end = offs[n + 1];
    const int deg = end - beg;
    const float hin = h_in[(long)n * HBLK + t];
    if (deg == 0) {  // DGL leaves h at h_in; residual doubles it
        h_out[(long)n * HBLK + t] = 2.f * hin;
        return;
    }
    const float sd = s_dst[n];
    __shared__ float red_m[128];
    __shared__ float red_s[128];

    // single online-softmax sweep: running max m, running sum ssum
    float m = -INFINITY, ssum = 0.f;
    for (int i = beg + t; i < end; i += 128) {
        float e = sd + s_src[src_sorted[i]];
        e = e > 0.f ? e : 0.01f * e;
        float nm = fmaxf(m, e);
        ssum = ssum * __expf(m - nm) + __expf(e - nm);
        m = nm;
    }
    red_m[t] = m;
    red_s[t] = ssum;
    __syncthreads();
    for (int s2 = 64; s2 > 0; s2 >>= 1) {
        if (t < s2) {
            float m1 = red_m[t], m2 = red_m[t + s2];
            float s1 = red_s[t], s2v = red_s[t + s2];
            if (m2 > m1) {
                float tmp = m1; m1 = m2; m2 = tmp;
                float ts = s1; s1 = s2v; s2v = ts;
            }
            // m1 >= m2; if m1 == -inf both empty
            red_m[t] = m1;
            red_s[t] = (m1 == -INFINITY) ? 0.f : s1 + s2v * __expf(m2 - m1);
        }
        __syncthreads();
    }
    m = red_m[0];
    const float inv = 1.f / fmaxf(red_s[0], 1e-16f);

    // weighted gather: acc = hs + sum alpha * z[src]; each thread owns one column
    float acc = hs[(long)n * HBLK + t];
    for (int i = beg; i < end; ++i) {
        int s = src_sorted[i];               // same addr all threads -> broadcast
        float e = sd + s_src[s];
        e = e > 0.f ? e : 0.01f * e;
        float w = __expf(e - m) * inv;
        acc += w * z[(long)s * HBLK + t];    // 512B coalesced row
    }
    h_out[(long)n * HBLK + t] = hin + acc;
}

// ---------------- output projection: out[N x OUT] = h @ W_out^T + b ----------------
__global__ void out_proj(const float* __restrict__ h, const float* __restrict__ W,
                         const float* __restrict__ b, float* __restrict__ out, int OUTD) {
    __shared__ float hr[HBLK];
    const int n = blockIdx.x;
    const int t = threadIdx.x;  // 128
    hr[t] = h[(long)n * HBLK + t];
    __syncthreads();
    if (t < OUTD) {
        float acc = b[t];
        const float* wr = W + t * HBLK;
#pragma unroll 4
        for (int k = 0; k < HBLK; ++k) acc += hr[k] * wr[k];
        out[(long)n * OUTD + t] = acc;
    }
}

extern "C" void kernel_launch(void* const* d_in, const int* in_sizes, int n_in,
                              void* d_out, int out_size, void* d_ws, size_t ws_size,
                              hipStream_t stream) {
    const float* feats = (const float*)d_in[0];
    // d_in[1] = e_w: unused (W_ee branch dead in reference)
    const float* maps  = (const float*)d_in[2];
    // d_in[3] = snorm_n: unused
    const int* src = (const int*)d_in[4];
    const int* dst = (const int*)d_in[5];
    const float* W_eh  = (const float*)d_in[6];
    const float* b_eh  = (const float*)d_in[7];
    // d_in[8], d_in[9] = W_ee, b_ee: unused
    const float* W_cat = (const float*)d_in[10];
    const float* b_cat = (const float*)d_in[11];
    const float* Ws1 = (const float*)d_in[12];
    const float* Wf1 = (const float*)d_in[13];
    const float* a1  = (const float*)d_in[14];
    const float* Ws2 = (const float*)d_in[15];
    const float* Wf2 = (const float*)d_in[16];
    const float* a2  = (const float*)d_in[17];
    const float* W_out = (const float*)d_in[18];
    const float* b_out = (const float*)d_in[19];

    const int N = in_sizes[3];            // snorm_n is (N,1)
    const int E = in_sizes[4];
    const int IN_DIM = in_sizes[0] / N;   // 24
    const int MAPD = in_sizes[2] / N;     // 512
    const int OUTD = in_sizes[19];        // 24

    // workspace layout (floats)
    float* ws = (float*)d_ws;
    const size_t NH = (size_t)N * HBLK;
    float* h0   = ws;            // N*128, later reused as hs
    float* hin  = h0 + NH;       // N*128
    float* zb   = hin + NH;      // N*128
    float* hout = zb + NH;       // N*128
    float* ssrc = hout + NH;     // N
    float* sdst = ssrc + N;      // N
    int* counts = (int*)(sdst + N);  // N
    int* offs   = counts + N;        // N+1
    int* cursor = offs + N + 1;      // N
    int* srcs   = cursor + N;        // E
    float* hs = h0;

    // ---- CSR by dst (rebuilt every call; ws is poisoned between calls) ----
    zero_counts<<<(N + 255) / 256, 256, 0, stream>>>(counts, N);
    hist_k<<<(E + 255) / 256, 256, 0, stream>>>(dst, counts, E);
    scan_k<<<1, 256, 0, stream>>>(counts, offs, cursor, N);
    fill_k<<<(E + 255) / 256, 256, 0, stream>>>(dst, src, cursor, srcs, E);

    const int gGrid = (N + 63) / 64;
    // ---- embedding front-end ----
    gemm_k<<<gGrid, 128, 0, stream>>>(feats, IN_DIM, IN_DIM, nullptr, 0, IN_DIM,
                                      W_eh, nullptr, IN_DIM, b_eh, h0, nullptr, N, 0);
    // fused concat: hin = relu([maps | h0] @ W_cat^T + b_cat)
    gemm_k<<<gGrid, 128, 0, stream>>>(maps, MAPD, MAPD, h0, HBLK, MAPD + HBLK,
                                      W_cat, nullptr, MAPD + HBLK, b_cat, hin, nullptr, N, 2);

    // ---- GAT layer 1: hin -> hout ----
    gemm_k<<<dim3(gGrid, 2), 128, 0, stream>>>(hin, HBLK, HBLK, nullptr, 0, HBLK,
                                               Ws1, Wf1, HBLK, nullptr, hs, zb, N, 0);
    compute_s<<<(N + 3) / 4, 256, 0, stream>>>(zb, a1, ssrc, sdst, N);
    gat_agg<<<N, 128, 0, stream>>>(hin, hs, zb, ssrc, sdst, offs, srcs, hout);

    // ---- GAT layer 2: hout -> hin ----
    gemm_k<<<dim3(gGrid, 2), 128, 0, stream>>>(hout, HBLK, HBLK, nullptr, 0, HBLK,
                                               Ws2, Wf2, HBLK, nullptr, hs, zb, N, 0);
    compute_s<<<(N + 3) / 4, 256, 0, stream>>>(zb, a2, ssrc, sdst, N);
    gat_agg<<<N, 128, 0, stream>>>(hout, hs, zb, ssrc, sdst, offs, srcs, hin);

    // ---- output projection ----
    out_proj<<<N, 128, 0, stream>>>(hin, W_out, b_out, (float*)d_out, OUTD);
}

// Round 4
// 642.334 us; speedup vs baseline: 1.0019x; 1.0019x over previous
//
#include <hip/hip_runtime.h>

#define HBLK 128  // hidden width, fixed by problem

typedef __attribute__((ext_vector_type(8))) short s8v;    // 8 bf16 in 4 VGPRs
typedef __attribute__((ext_vector_type(4))) float f32x4;  // MFMA accumulator

// split fp32 into bf16 hi + lo (truncation; residual <= 2^-16 |x|)
__device__ inline void split2(float x, short& h, short& l) {
    unsigned hb = __float_as_uint(x) & 0xFFFF0000u;
    float hf = __uint_as_float(hb);
    float lf = x - hf;
    h = (short)(hb >> 16);
    l = (short)(__float_as_uint(lf) >> 16);
}

// ---------------- CSR build ----------------
__global__ void zero_counts(int* counts, int n) {
    int i = blockIdx.x * 256 + threadIdx.x;
    if (i < n) counts[i] = 0;
}

__global__ void hist_k(const int* __restrict__ dst, int* counts, int E) {
    int e = blockIdx.x * 256 + threadIdx.x;
    if (e < E) atomicAdd(&counts[dst[e]], 1);
}

__global__ void scan_k(const int* __restrict__ counts, int* offs, int* cursor, int n) {
    __shared__ int lds[256];
    const int t = threadIdx.x;
    const int CH = (n + 255) / 256;
    const int base = t * CH;
    int s = 0;
    for (int i = 0; i < CH; ++i) {
        int idx = base + i;
        if (idx < n) s += counts[idx];
    }
    lds[t] = s;
    __syncthreads();
    for (int off = 1; off < 256; off <<= 1) {
        int add = (t >= off) ? lds[t - off] : 0;
        __syncthreads();
        lds[t] += add;
        __syncthreads();
    }
    int run = lds[t] - s;  // exclusive prefix
    for (int i = 0; i < CH; ++i) {
        int idx = base + i;
        if (idx < n) {
            offs[idx] = run;
            cursor[idx] = run;
            run += counts[idx];
        }
    }
    if (t == 255) offs[n] = lds[255];
}

__global__ void fill_k(const int* __restrict__ dst, const int* __restrict__ src,
                       int* cursor, int* __restrict__ src_sorted, int E) {
    int e = blockIdx.x * 256 + threadIdx.x;
    if (e < E) {
        int p = atomicAdd(&cursor[dst[e]], 1);
        src_sorted[p] = src[e];
    }
}

// ---------------- fp32 -> bf16 hi/lo split (with zero-pad region) ----------------
// dst[r*dstld + c] = split(src[r*srcld + c]) for c < kin, else 0; c in [0, cols)
__global__ void split_k(const float* __restrict__ src, int srcld, int kin,
                        short* __restrict__ dh, short* __restrict__ dl, int dstld,
                        int rows, int cols) {
    long i = (long)blockIdx.x * 256 + threadIdx.x;
    if (i >= (long)rows * cols) return;
    int r = (int)(i / cols), c = (int)(i % cols);
    float x = (c < kin) ? src[(long)r * srcld + c] : 0.f;
    short h, l;
    split2(x, h, l);
    dh[(long)r * dstld + c] = h;
    dl[(long)r * dstld + c] = l;
}

// ---------------- split-fp32 MFMA GEMM ----------------
// C[M x 128] = act(A @ W^T + bias)
// A: [M x K] as bf16 hi/lo (row-major, lda); W: [128 x K] bf16 hi/lo (row-major).
// Product emulated as ah*wh + ah*wl + al*wh (fp32 accumulate).
// blockIdx.y selects (W1,C1f) vs (W2,C2f) for the dual Ws/Wf case.
// Optional fp32 out Cf (ld 128) and bf16 hi/lo out Ch/Cl (ld ldc).
// No LDS, no barriers: fragments load straight global->VGPR (A and W^T fragments
// are both 8 contiguous k-elems of a row-major row for mfma_f32_16x16x32_bf16).
__global__ __launch_bounds__(256) void gemm_mfma(
    const short* __restrict__ Ah, const short* __restrict__ Al, int lda, int K,
    const short* __restrict__ W1h, const short* __restrict__ W1l,
    const short* __restrict__ W2h, const short* __restrict__ W2l,
    const float* __restrict__ bias,
    float* __restrict__ C1f, float* __restrict__ C2f,
    short* __restrict__ Ch, short* __restrict__ Cl, int ldc,
    int M, int relu)
{
    const short* __restrict__ Wh = blockIdx.y ? W2h : W1h;
    const short* __restrict__ Wl = blockIdx.y ? W2l : W1l;
    float* __restrict__ Cf = blockIdx.y ? C2f : C1f;
    const int wv = threadIdx.x >> 6;
    const int lane = threadIdx.x & 63;
    const int l16 = lane & 15;
    const int quad = lane >> 4;
    const int m0 = blockIdx.x * 64 + wv * 16;   // this wave's 16-row tile
    int ra = m0 + l16;
    if (ra >= M) ra = M - 1;                    // clamp loads; stores guarded
    const long abase = (long)ra * lda + quad * 8;

    f32x4 acc[8];
#pragma unroll
    for (int j = 0; j < 8; ++j) acc[j] = (f32x4){0.f, 0.f, 0.f, 0.f};

    for (int kb = 0; kb < K; kb += 32) {
        const s8v a_h = *(const s8v*)(Ah + abase + kb);
        const s8v a_l = *(const s8v*)(Al + abase + kb);
#pragma unroll
        for (int j = 0; j < 8; ++j) {
            const long wo = (long)(j * 16 + l16) * K + quad * 8 + kb;
            const s8v w_h = *(const s8v*)(Wh + wo);
            const s8v w_l = *(const s8v*)(Wl + wo);
            acc[j] = __builtin_amdgcn_mfma_f32_16x16x32_bf16(a_h, w_h, acc[j], 0, 0, 0);
            acc[j] = __builtin_amdgcn_mfma_f32_16x16x32_bf16(a_h, w_l, acc[j], 0, 0, 0);
            acc[j] = __builtin_amdgcn_mfma_f32_16x16x32_bf16(a_l, w_h, acc[j], 0, 0, 0);
        }
    }

    // C/D layout: col = lane&15, row = quad*4 + reg  (verified m89/m91)
#pragma unroll
    for (int r = 0; r < 4; ++r) {
        const int gr = m0 + quad * 4 + r;
        if (gr >= M) continue;
#pragma unroll
        for (int j = 0; j < 8; ++j) {
            const int col = j * 16 + l16;
            float v = acc[j][r];
            if (bias) v += bias[col];
            if (relu) v = fmaxf(v, 0.f);
            if (Cf) Cf[(long)gr * HBLK + col] = v;
            if (Ch) {
                short h, l;
                split2(v, h, l);
                Ch[(long)gr * ldc + col] = h;
                Cl[(long)gr * ldc + col] = l;
            }
        }
    }
}

// ---------------- per-node attention-score halves: s_src = z@a[:128], s_dst = z@a[128:] ----------------
__global__ void compute_s(const float* __restrict__ z, const float* __restrict__ a,
                          float* __restrict__ s_src, float* __restrict__ s_dst, int N) {
    const int wave = threadIdx.x >> 6;
    const int lane = threadIdx.x & 63;
    const int n = blockIdx.x * 4 + wave;
    if (n >= N) return;
    const float* zr = z + (long)n * HBLK;
    float v0 = zr[lane], v1 = zr[lane + 64];
    float ss = v0 * a[lane] + v1 * a[lane + 64];
    float sd = v0 * a[128 + lane] + v1 * a[192 + lane];
#pragma unroll
    for (int off = 32; off > 0; off >>= 1) {
        ss += __shfl_down(ss, off);
        sd += __shfl_down(sd, off);
    }
    if (lane == 0) {
        s_src[n] = ss;
        s_dst[n] = sd;
    }
}

// ---------------- GAT edge softmax + aggregation; one block (128 thr) per dst node ----------------
// Optionally also emits bf16 hi/lo of the output (feeds next layer's GEMM).
__global__ void gat_agg(const float* __restrict__ h_in, const float* __restrict__ hs,
                        const float* __restrict__ z,
                        const float* __restrict__ s_src, const float* __restrict__ s_dst,
                        const int* __restrict__ offs, const int* __restrict__ src_sorted,
                        float* __restrict__ h_out,
                        short* __restrict__ ho_h, short* __restrict__ ho_l) {
    const int n = blockIdx.x;
    const int t = threadIdx.x;  // 128
    const int beg = offs[n], end = offs[n + 1];
    const int deg = end - beg;
    const float hin = h_in[(long)n * HBLK + t];
    if (deg == 0) {  // DGL leaves h at h_in; residual doubles it
        float v = 2.f * hin;
        h_out[(long)n * HBLK + t] = v;
        if (ho_h) {
            short h, l;
            split2(v, h, l);
            ho_h[(long)n * HBLK + t] = h;
            ho_l[(long)n * HBLK + t] = l;
        }
        return;
    }
    const float sd = s_dst[n];
    __shared__ float red_m[128];
    __shared__ float red_s[128];

    // online-softmax sweep
    float m = -INFINITY, ssum = 0.f;
    for (int i = beg + t; i < end; i += 128) {
        float e = sd + s_src[src_sorted[i]];
        e = e > 0.f ? e : 0.01f * e;
        float nm = fmaxf(m, e);
        ssum = ssum * __expf(m - nm) + __expf(e - nm);
        m = nm;
    }
    red_m[t] = m;
    red_s[t] = ssum;
    __syncthreads();
    for (int s2 = 64; s2 > 0; s2 >>= 1) {
        if (t < s2) {
            float m1 = red_m[t], m2 = red_m[t + s2];
            float s1 = red_s[t], s2v = red_s[t + s2];
            if (m2 > m1) {
                float tmp = m1; m1 = m2; m2 = tmp;
                float ts = s1; s1 = s2v; s2v = ts;
            }
            red_m[t] = m1;
            red_s[t] = (m1 == -INFINITY) ? 0.f : s1 + s2v * __expf(m2 - m1);
        }
        __syncthreads();
    }
    m = red_m[0];
    const float inv = 1.f / fmaxf(red_s[0], 1e-16f);

    // weighted gather: acc = hs + sum alpha * z[src]; each thread owns one column
    float acc = hs[(long)n * HBLK + t];
    for (int i = beg; i < end; ++i) {
        int s = src_sorted[i];               // same addr all threads -> broadcast
        float e = sd + s_src[s];
        e = e > 0.f ? e : 0.01f * e;
        float w = __expf(e - m) * inv;
        acc += w * z[(long)s * HBLK + t];    // 512B coalesced row
    }
    float v = hin + acc;
    h_out[(long)n * HBLK + t] = v;
    if (ho_h) {
        short h, l;
        split2(v, h, l);
        ho_h[(long)n * HBLK + t] = h;
        ho_l[(long)n * HBLK + t] = l;
    }
}

// ---------------- output projection: out[N x OUT] = h @ W_out^T + b ----------------
__global__ void out_proj(const float* __restrict__ h, const float* __restrict__ W,
                         const float* __restrict__ b, float* __restrict__ out, int OUTD) {
    __shared__ float hr[HBLK];
    const int n = blockIdx.x;
    const int t = threadIdx.x;  // 128
    hr[t] = h[(long)n * HBLK + t];
    __syncthreads();
    if (t < OUTD) {
        float acc = b[t];
        const float* wr = W + t * HBLK;
#pragma unroll 4
        for (int k = 0; k < HBLK; ++k) acc += hr[k] * wr[k];
        out[(long)n * OUTD + t] = acc;
    }
}

extern "C" void kernel_launch(void* const* d_in, const int* in_sizes, int n_in,
                              void* d_out, int out_size, void* d_ws, size_t ws_size,
                              hipStream_t stream) {
    const float* feats = (const float*)d_in[0];
    const float* maps  = (const float*)d_in[2];
    const int* src = (const int*)d_in[4];
    const int* dst = (const int*)d_in[5];
    const float* W_eh  = (const float*)d_in[6];
    const float* b_eh  = (const float*)d_in[7];
    const float* W_cat = (const float*)d_in[10];
    const float* b_cat = (const float*)d_in[11];
    const float* Ws1 = (const float*)d_in[12];
    const float* Wf1 = (const float*)d_in[13];
    const float* a1  = (const float*)d_in[14];
    const float* Ws2 = (const float*)d_in[15];
    const float* Wf2 = (const float*)d_in[16];
    const float* a2  = (const float*)d_in[17];
    const float* W_out = (const float*)d_in[18];
    const float* b_out = (const float*)d_in[19];

    const int N = in_sizes[3];            // snorm_n is (N,1)
    const int E = in_sizes[4];
    const int IN_DIM = in_sizes[0] / N;   // 24
    const int MAPD = in_sizes[2] / N;     // 512
    const int OUTD = in_sizes[19];        // 24
    const int KCAT = MAPD + HBLK;         // 640
    const int KIN_PAD = 32;               // 24 padded to one K-chunk

    // ---- workspace layout ----
    char* p = (char*)d_ws;
    const size_t NH = (size_t)N * HBLK;
    float* hin = (float*)p;            p += NH * 4;                 // fp32 h after concat+relu
    short* hb_h = (short*)p;           p += NH * 2;                 // bf16 hi of current layer input
    short* hb_l = (short*)p;           p += NH * 2;
    short* fA_h = (short*)p;           p += (size_t)N * KIN_PAD * 2;
    short* fA_l = (short*)p;           p += (size_t)N * KIN_PAD * 2;
    short* Weh_h = (short*)p;          p += (size_t)HBLK * KIN_PAD * 2;
    short* Weh_l = (short*)p;          p += (size_t)HBLK * KIN_PAD * 2;
    short* Wcat_h = (short*)p;         p += (size_t)HBLK * KCAT * 2;
    short* Wcat_l = (short*)p;         p += (size_t)HBLK * KCAT * 2;
    short* Wly_h[4]; short* Wly_l[4];
    for (int i = 0; i < 4; ++i) {
        Wly_h[i] = (short*)p;          p += (size_t)HBLK * HBLK * 2;
        Wly_l[i] = (short*)p;          p += (size_t)HBLK * HBLK * 2;
    }
    float* ssrc = (float*)p;           p += (size_t)N * 4;
    float* sdst = (float*)p;           p += (size_t)N * 4;
    int* counts = (int*)p;             p += (size_t)N * 4;
    int* cursor = (int*)p;             p += (size_t)N * 4;
    int* srcs   = (int*)p;             p += (size_t)E * 4;
    int* offs   = (int*)p;             p += (size_t)(N + 1) * 4;
    p = (char*)(((uintptr_t)p + 15) & ~(uintptr_t)15);
    // BIG region: cat hi/lo (2 * N*640 shorts) alive until concat GEMM,
    // then reused as hs/zb/hout fp32 (3 * NH floats <= that size).
    short* cat_h = (short*)p;
    short* cat_l = cat_h + (size_t)N * KCAT;
    float* hs   = (float*)p;
    float* zb   = hs + NH;
    float* hout = zb + NH;

    // ---- CSR by dst (rebuilt every call; ws is poisoned between calls) ----
    zero_counts<<<(N + 255) / 256, 256, 0, stream>>>(counts, N);
    hist_k<<<(E + 255) / 256, 256, 0, stream>>>(dst, counts, E);
    scan_k<<<1, 256, 0, stream>>>(counts, offs, cursor, N);
    fill_k<<<(E + 255) / 256, 256, 0, stream>>>(dst, src, cursor, srcs, E);

    // ---- bf16 hi/lo conversions ----
    {
        long t1 = (long)N * KIN_PAD;
        split_k<<<(t1 + 255) / 256, 256, 0, stream>>>(feats, IN_DIM, IN_DIM, fA_h, fA_l, KIN_PAD, N, KIN_PAD);
        long t2 = (long)N * MAPD;
        split_k<<<(t2 + 255) / 256, 256, 0, stream>>>(maps, MAPD, MAPD, cat_h, cat_l, KCAT, N, MAPD);
        long t3 = (long)HBLK * KIN_PAD;
        split_k<<<(t3 + 255) / 256, 256, 0, stream>>>(W_eh, IN_DIM, IN_DIM, Weh_h, Weh_l, KIN_PAD, HBLK, KIN_PAD);
        long t4 = (long)HBLK * KCAT;
        split_k<<<(t4 + 255) / 256, 256, 0, stream>>>(W_cat, KCAT, KCAT, Wcat_h, Wcat_l, KCAT, HBLK, KCAT);
        const float* Wly[4] = {Ws1, Wf1, Ws2, Wf2};
        long t5 = (long)HBLK * HBLK;
        for (int i = 0; i < 4; ++i)
            split_k<<<(t5 + 255) / 256, 256, 0, stream>>>(Wly[i], HBLK, HBLK, Wly_h[i], Wly_l[i], HBLK, HBLK, HBLK);
    }

    const int gGrid = (N + 63) / 64;
    // ---- front GEMM: h0 = feats@W_eh^T + b_eh -> bf16 into cat cols [512,640) ----
    gemm_mfma<<<dim3(gGrid, 1), 256, 0, stream>>>(
        fA_h, fA_l, KIN_PAD, KIN_PAD, Weh_h, Weh_l, nullptr, nullptr, b_eh,
        nullptr, nullptr, cat_h + MAPD, cat_l + MAPD, KCAT, N, 0);
    // ---- concat GEMM: hin = relu(cat @ W_cat^T + b_cat); also emit bf16 pair ----
    gemm_mfma<<<dim3(gGrid, 1), 256, 0, stream>>>(
        cat_h, cat_l, KCAT, KCAT, Wcat_h, Wcat_l, nullptr, nullptr, b_cat,
        hin, nullptr, hb_h, hb_l, HBLK, N, 1);

    // ---- GAT layer 1 ----
    gemm_mfma<<<dim3(gGrid, 2), 256, 0, stream>>>(
        hb_h, hb_l, HBLK, HBLK, Wly_h[0], Wly_l[0], Wly_h[1], Wly_l[1], nullptr,
        hs, zb, nullptr, nullptr, HBLK, N, 0);
    compute_s<<<(N + 3) / 4, 256, 0, stream>>>(zb, a1, ssrc, sdst, N);
    gat_agg<<<N, 128, 0, stream>>>(hin, hs, zb, ssrc, sdst, offs, srcs, hout, hb_h, hb_l);

    // ---- GAT layer 2 ----
    gemm_mfma<<<dim3(gGrid, 2), 256, 0, stream>>>(
        hb_h, hb_l, HBLK, HBLK, Wly_h[2], Wly_l[2], Wly_h[3], Wly_l[3], nullptr,
        hs, zb, nullptr, nullptr, HBLK, N, 0);
    compute_s<<<(N + 3) / 4, 256, 0, stream>>>(zb, a2, ssrc, sdst, N);
    gat_agg<<<N, 128, 0, stream>>>(hout, hs, zb, ssrc, sdst, offs, srcs, hin, nullptr, nullptr);

    // ---- output projection ----
    out_proj<<<N, 128, 0, stream>>>(hin, W_out, b_out, (float*)d_out, OUTD);
}

// Round 5
// 488.468 us; speedup vs baseline: 1.3175x; 1.3150x over previous
//
#include <hip/hip_runtime.h>

#define HBLK 128  // hidden width, fixed by problem

typedef __attribute__((ext_vector_type(8))) short s8v;    // 8 bf16 in 4 VGPRs
typedef __attribute__((ext_vector_type(4))) float f32x4;  // MFMA accumulator

// split fp32 into bf16 hi + lo (truncation; residual <= 2^-16 |x|)
__device__ inline void split2(float x, short& h, short& l) {
    unsigned hb = __float_as_uint(x) & 0xFFFF0000u;
    float hf = __uint_as_float(hb);
    float lf = x - hf;
    h = (short)(hb >> 16);
    l = (short)(__float_as_uint(lf) >> 16);
}

// ---------------- CSR build ----------------
__global__ void zero_counts(int* counts, int n) {
    int i = blockIdx.x * 256 + threadIdx.x;
    if (i < n) counts[i] = 0;
}

__global__ void hist_k(const int* __restrict__ dst, int* counts, int E) {
    int e = blockIdx.x * 256 + threadIdx.x;
    if (e < E) atomicAdd(&counts[dst[e]], 1);
}

__global__ void scan_k(const int* __restrict__ counts, int* offs, int* cursor, int n) {
    __shared__ int lds[256];
    const int t = threadIdx.x;
    const int CH = (n + 255) / 256;
    const int base = t * CH;
    int s = 0;
    for (int i = 0; i < CH; ++i) {
        int idx = base + i;
        if (idx < n) s += counts[idx];
    }
    lds[t] = s;
    __syncthreads();
    for (int off = 1; off < 256; off <<= 1) {
        int add = (t >= off) ? lds[t - off] : 0;
        __syncthreads();
        lds[t] += add;
        __syncthreads();
    }
    int run = lds[t] - s;  // exclusive prefix
    for (int i = 0; i < CH; ++i) {
        int idx = base + i;
        if (idx < n) {
            offs[idx] = run;
            cursor[idx] = run;
            run += counts[idx];
        }
    }
    if (t == 255) offs[n] = lds[255];
}

__global__ void fill_k(const int* __restrict__ dst, const int* __restrict__ src,
                       int* cursor, int* __restrict__ src_sorted, int E) {
    int e = blockIdx.x * 256 + threadIdx.x;
    if (e < E) {
        int p = atomicAdd(&cursor[dst[e]], 1);
        src_sorted[p] = src[e];
    }
}

// ---------------- weight split + pack into MFMA-fragment order ----------------
// W: [C=128 rows][kin cols] fp32 row-major -> dh/dl packed so a wave's fragment
// load for (chunk=k/32, j=c/16) is contiguous: off = ((chunk*8+j)*64 + lane)*8 + t
// where lane = quad*16 + l16, c = j*16+l16, k = chunk*32 + quad*8 + t. K padded w/ 0.
__global__ void split_w_pack(const float* __restrict__ W, int ldw, int kin,
                             short* __restrict__ dh, short* __restrict__ dl,
                             int C, int K) {
    long i = (long)blockIdx.x * 256 + threadIdx.x;
    if (i >= (long)C * K) return;
    int c = (int)(i / K), k = (int)(i % K);
    float x = (k < kin) ? W[(long)c * ldw + k] : 0.f;
    short h, l;
    split2(x, h, l);
    int j = c >> 4, l16 = c & 15;
    int chunk = k >> 5, quad = (k >> 3) & 3, t = k & 7;
    long off = (((long)(chunk * 8 + j) * 64) + quad * 16 + l16) * 8 + t;
    dh[off] = h;
    dl[off] = l;
}

// ---------------- split-fp32 MFMA GEMM, software-pipelined, no LDS ----------------
// C[M x 128] = act([A1|A2] @ W^T + bias); A fp32 row-major (split to bf16 hi/lo
// in-register), W pre-split+packed. Emulation: ah*wh + ah*wl + al*wh.
// K1 and Kin multiples of 8; K (padded) multiple of 64. blockIdx.y picks W1/C1 vs W2/C2.
__global__ __launch_bounds__(256, 2) void gemm_mfma(
    const float* __restrict__ A1, int lda1, int K1,
    const float* __restrict__ A2, int lda2, int Kin,
    int K,
    const short* __restrict__ W1h, const short* __restrict__ W1l,
    const short* __restrict__ W2h, const short* __restrict__ W2l,
    const float* __restrict__ bias,
    float* __restrict__ C1f, float* __restrict__ C2f,
    int M, int relu)
{
    const short* __restrict__ Wh = blockIdx.y ? W2h : W1h;
    const short* __restrict__ Wl = blockIdx.y ? W2l : W1l;
    float* __restrict__ Cf = blockIdx.y ? C2f : C1f;
    const int wv = threadIdx.x >> 6;
    const int lane = threadIdx.x & 63;
    const int l16 = lane & 15;
    const int quad = lane >> 4;
    const int m0 = blockIdx.x * 64 + wv * 16;   // this wave's 16-row tile
    int ra = m0 + l16;
    if (ra >= M) ra = M - 1;                    // clamp loads; stores guarded
    const long r1 = (long)ra * lda1;
    const long r2 = (long)ra * lda2;

    f32x4 acc[8];
#pragma unroll
    for (int j = 0; j < 8; ++j) acc[j] = (f32x4){0.f, 0.f, 0.f, 0.f};

    // raw A loads (fp32) for one chunk: 8 floats at col0 = kb + quad*8
#define LOAD_A_RAW(dst0, dst1, kb)                                              \
    {                                                                           \
        const int col0 = (kb) + quad * 8;                                       \
        if (col0 < K1) {                                                        \
            const float* ap = A1 + r1 + col0;                                   \
            dst0 = *(const float4*)ap;                                          \
            dst1 = *(const float4*)(ap + 4);                                    \
        } else if (col0 < Kin) {                                                \
            const float* ap = A2 + r2 + (col0 - K1);                            \
            dst0 = *(const float4*)ap;                                          \
            dst1 = *(const float4*)(ap + 4);                                    \
        } else {                                                                \
            dst0 = make_float4(0.f, 0.f, 0.f, 0.f);                             \
            dst1 = make_float4(0.f, 0.f, 0.f, 0.f);                             \
        }                                                                       \
    }

#define LOAD_W(wharr, wlarr, kb)                                                \
    {                                                                           \
        const long cb = (long)((kb) >> 5) * 4096 + (long)lane * 8;              \
        _Pragma("unroll")                                                       \
        for (int j = 0; j < 8; ++j) {                                           \
            wharr[j] = *(const s8v*)(Wh + cb + j * 512);                        \
            wlarr[j] = *(const s8v*)(Wl + cb + j * 512);                        \
        }                                                                       \
    }

#define SPLIT_A(a0, a1, ah, al)                                                 \
    {                                                                           \
        float vv[8];                                                            \
        *(float4*)&vv[0] = a0;                                                  \
        *(float4*)&vv[4] = a1;                                                  \
        _Pragma("unroll")                                                       \
        for (int e = 0; e < 8; ++e) {                                           \
            short hh, ll;                                                       \
            split2(vv[e], hh, ll);                                              \
            ah[e] = hh;                                                         \
            al[e] = ll;                                                         \
        }                                                                       \
    }

#define DO_MFMA(ah, al, wharr, wlarr)                                           \
    {                                                                           \
        _Pragma("unroll")                                                       \
        for (int j = 0; j < 8; ++j) {                                           \
            acc[j] = __builtin_amdgcn_mfma_f32_16x16x32_bf16(ah, wharr[j], acc[j], 0, 0, 0); \
            acc[j] = __builtin_amdgcn_mfma_f32_16x16x32_bf16(ah, wlarr[j], acc[j], 0, 0, 0); \
            acc[j] = __builtin_amdgcn_mfma_f32_16x16x32_bf16(al, wharr[j], acc[j], 0, 0, 0); \
        }                                                                       \
    }

    float4 a0r0, a0r1, a1r0, a1r1;
    s8v wh0[8], wl0[8], wh1[8], wl1[8];
    s8v ah, al;

    // preload chunk 0
    LOAD_A_RAW(a0r0, a0r1, 0)
    LOAD_W(wh0, wl0, 0)

    for (int kb = 0; kb < K; kb += 64) {
        // prefetch chunk kb+32 (always exists: K % 64 == 0)
        LOAD_A_RAW(a1r0, a1r1, kb + 32)
        LOAD_W(wh1, wl1, kb + 32)
        // compute chunk kb
        SPLIT_A(a0r0, a0r1, ah, al)
        DO_MFMA(ah, al, wh0, wl0)
        // prefetch chunk kb+64 (or harmless reload of 0 on last iter)
        const int kn = (kb + 64 < K) ? kb + 64 : 0;
        LOAD_A_RAW(a0r0, a0r1, kn)
        LOAD_W(wh0, wl0, kn)
        // compute chunk kb+32
        SPLIT_A(a1r0, a1r1, ah, al)
        DO_MFMA(ah, al, wh1, wl1)
    }

    // C/D layout: col = lane&15, row = quad*4 + reg  (verified m89/m91)
#pragma unroll
    for (int r = 0; r < 4; ++r) {
        const int gr = m0 + quad * 4 + r;
        if (gr >= M) continue;
#pragma unroll
        for (int j = 0; j < 8; ++j) {
            const int col = j * 16 + l16;
            float v = acc[j][r];
            if (bias) v += bias[col];
            if (relu) v = fmaxf(v, 0.f);
            Cf[(long)gr * HBLK + col] = v;
        }
    }
#undef LOAD_A_RAW
#undef LOAD_W
#undef SPLIT_A
#undef DO_MFMA
}

// ---------------- per-node attention-score halves: s_src = z@a[:128], s_dst = z@a[128:] ----------------
__global__ void compute_s(const float* __restrict__ z, const float* __restrict__ a,
                          float* __restrict__ s_src, float* __restrict__ s_dst, int N) {
    const int wave = threadIdx.x >> 6;
    const int lane = threadIdx.x & 63;
    const int n = blockIdx.x * 4 + wave;
    if (n >= N) return;
    const float* zr = z + (long)n * HBLK;
    float v0 = zr[lane], v1 = zr[lane + 64];
    float ss = v0 * a[lane] + v1 * a[lane + 64];
    float sd = v0 * a[128 + lane] + v1 * a[192 + lane];
#pragma unroll
    for (int off = 32; off > 0; off >>= 1) {
        ss += __shfl_down(ss, off);
        sd += __shfl_down(sd, off);
    }
    if (lane == 0) {
        s_src[n] = ss;
        s_dst[n] = sd;
    }
}

// ---------------- GAT edge softmax + aggregation; one block (128 thr) per dst node ----------------
__global__ void gat_agg(const float* __restrict__ h_in, const float* __restrict__ hs,
                        const float* __restrict__ z,
                        const float* __restrict__ s_src, const float* __restrict__ s_dst,
                        const int* __restrict__ offs, const int* __restrict__ src_sorted,
                        float* __restrict__ h_out) {
    const int n = blockIdx.x;
    const int t = threadIdx.x;  // 128
    const int beg = offs[n], end = offs[n + 1];
    const int deg = end - beg;
    const float hin = h_in[(long)n * HBLK + t];
    if (deg == 0) {  // DGL leaves h at h_in; residual doubles it
        h_out[(long)n * HBLK + t] = 2.f * hin;
        return;
    }
    const float sd = s_dst[n];
    __shared__ float red_m[128];
    __shared__ float red_s[128];

    // online-softmax sweep
    float m = -INFINITY, ssum = 0.f;
    for (int i = beg + t; i < end; i += 128) {
        float e = sd + s_src[src_sorted[i]];
        e = e > 0.f ? e : 0.01f * e;
        float nm = fmaxf(m, e);
        ssum = ssum * __expf(m - nm) + __expf(e - nm);
        m = nm;
    }
    red_m[t] = m;
    red_s[t] = ssum;
    __syncthreads();
    for (int s2 = 64; s2 > 0; s2 >>= 1) {
        if (t < s2) {
            float m1 = red_m[t], m2 = red_m[t + s2];
            float s1 = red_s[t], s2v = red_s[t + s2];
            if (m2 > m1) {
                float tmp = m1; m1 = m2; m2 = tmp;
                float ts = s1; s1 = s2v; s2v = ts;
            }
            red_m[t] = m1;
            red_s[t] = (m1 == -INFINITY) ? 0.f : s1 + s2v * __expf(m2 - m1);
        }
        __syncthreads();
    }
    m = red_m[0];
    const float inv = 1.f / fmaxf(red_s[0], 1e-16f);

    // weighted gather: acc = hs + sum alpha * z[src]; each thread owns one column.
    // unroll by 2 to keep two 512B row-loads in flight
    float acc = hs[(long)n * HBLK + t];
    int i = beg;
    for (; i + 2 <= end; i += 2) {
        int s0 = src_sorted[i], s1 = src_sorted[i + 1];
        float e0 = sd + s_src[s0];
        float e1 = sd + s_src[s1];
        e0 = e0 > 0.f ? e0 : 0.01f * e0;
        e1 = e1 > 0.f ? e1 : 0.01f * e1;
        float z0 = z[(long)s0 * HBLK + t];
        float z1 = z[(long)s1 * HBLK + t];
        acc += __expf(e0 - m) * inv * z0;
        acc += __expf(e1 - m) * inv * z1;
    }
    if (i < end) {
        int s0 = src_sorted[i];
        float e0 = sd + s_src[s0];
        e0 = e0 > 0.f ? e0 : 0.01f * e0;
        acc += __expf(e0 - m) * inv * z[(long)s0 * HBLK + t];
    }
    h_out[(long)n * HBLK + t] = hin + acc;
}

// ---------------- output projection: out[N x OUT] = h @ W_out^T + b ----------------
__global__ void out_proj(const float* __restrict__ h, const float* __restrict__ W,
                         const float* __restrict__ b, float* __restrict__ out, int OUTD) {
    __shared__ float hr[HBLK];
    const int n = blockIdx.x;
    const int t = threadIdx.x;  // 128
    hr[t] = h[(long)n * HBLK + t];
    __syncthreads();
    if (t < OUTD) {
        float acc = b[t];
        const float* wr = W + t * HBLK;
#pragma unroll 4
        for (int k = 0; k < HBLK; ++k) acc += hr[k] * wr[k];
        out[(long)n * OUTD + t] = acc;
    }
}

extern "C" void kernel_launch(void* const* d_in, const int* in_sizes, int n_in,
                              void* d_out, int out_size, void* d_ws, size_t ws_size,
                              hipStream_t stream) {
    const float* feats = (const float*)d_in[0];
    const float* maps  = (const float*)d_in[2];
    const int* src = (const int*)d_in[4];
    const int* dst = (const int*)d_in[5];
    const float* W_eh  = (const float*)d_in[6];
    const float* b_eh  = (const float*)d_in[7];
    const float* W_cat = (const float*)d_in[10];
    const float* b_cat = (const float*)d_in[11];
    const float* Ws1 = (const float*)d_in[12];
    const float* Wf1 = (const float*)d_in[13];
    const float* a1  = (const float*)d_in[14];
    const float* Ws2 = (const float*)d_in[15];
    const float* Wf2 = (const float*)d_in[16];
    const float* a2  = (const float*)d_in[17];
    const float* W_out = (const float*)d_in[18];
    const float* b_out = (const float*)d_in[19];

    const int N = in_sizes[3];            // snorm_n is (N,1)
    const int E = in_sizes[4];
    const int IN_DIM = in_sizes[0] / N;   // 24
    const int MAPD = in_sizes[2] / N;     // 512
    const int OUTD = in_sizes[19];        // 24
    const int KCAT = MAPD + HBLK;         // 640 (multiple of 64)
    const int KIN_PAD = 64;               // 24 padded to pipeline granularity

    // ---- workspace layout ----
    char* p = (char*)d_ws;
    const size_t NH = (size_t)N * HBLK;
    float* hin  = (float*)p;  p += NH * 4;
    float* h0   = (float*)p;  p += NH * 4;
    float* hs   = (float*)p;  p += NH * 4;
    float* zb   = (float*)p;  p += NH * 4;
    float* hout = (float*)p;  p += NH * 4;
    float* ssrc = (float*)p;  p += (size_t)N * 4;
    float* sdst = (float*)p;  p += (size_t)N * 4;
    int* counts = (int*)p;    p += (size_t)N * 4;
    int* cursor = (int*)p;    p += (size_t)N * 4;
    int* offs   = (int*)p;    p += (size_t)(N + 1) * 4;
    int* srcs   = (int*)p;    p += (size_t)E * 4;
    p = (char*)(((uintptr_t)p + 15) & ~(uintptr_t)15);
    short* Weh_h  = (short*)p; p += (size_t)HBLK * KIN_PAD * 2;
    short* Weh_l  = (short*)p; p += (size_t)HBLK * KIN_PAD * 2;
    short* Wcat_h = (short*)p; p += (size_t)HBLK * KCAT * 2;
    short* Wcat_l = (short*)p; p += (size_t)HBLK * KCAT * 2;
    short* Wly_h[4]; short* Wly_l[4];
    for (int i = 0; i < 4; ++i) {
        Wly_h[i] = (short*)p;  p += (size_t)HBLK * HBLK * 2;
        Wly_l[i] = (short*)p;  p += (size_t)HBLK * HBLK * 2;
    }

    // ---- CSR by dst (rebuilt every call; ws is poisoned between calls) ----
    zero_counts<<<(N + 255) / 256, 256, 0, stream>>>(counts, N);
    hist_k<<<(E + 255) / 256, 256, 0, stream>>>(dst, counts, E);
    scan_k<<<1, 256, 0, stream>>>(counts, offs, cursor, N);
    fill_k<<<(E + 255) / 256, 256, 0, stream>>>(dst, src, cursor, srcs, E);

    // ---- weight split+pack (small) ----
    split_w_pack<<<(HBLK * KIN_PAD + 255) / 256, 256, 0, stream>>>(
        W_eh, IN_DIM, IN_DIM, Weh_h, Weh_l, HBLK, KIN_PAD);
    split_w_pack<<<(HBLK * KCAT + 255) / 256, 256, 0, stream>>>(
        W_cat, KCAT, KCAT, Wcat_h, Wcat_l, HBLK, KCAT);
    {
        const float* Wly[4] = {Ws1, Wf1, Ws2, Wf2};
        for (int i = 0; i < 4; ++i)
            split_w_pack<<<(HBLK * HBLK + 255) / 256, 256, 0, stream>>>(
                Wly[i], HBLK, HBLK, Wly_h[i], Wly_l[i], HBLK, HBLK);
    }

    const int gGrid = (N + 63) / 64;
    // ---- front GEMM: h0 = feats @ W_eh^T + b_eh ----
    gemm_mfma<<<dim3(gGrid, 1), 256, 0, stream>>>(
        feats, IN_DIM, IN_DIM, nullptr, 0, IN_DIM, KIN_PAD,
        Weh_h, Weh_l, nullptr, nullptr, b_eh, h0, nullptr, N, 0);
    // ---- concat GEMM: hin = relu([maps | h0] @ W_cat^T + b_cat) ----
    gemm_mfma<<<dim3(gGrid, 1), 256, 0, stream>>>(
        maps, MAPD, MAPD, h0, HBLK, KCAT, KCAT,
        Wcat_h, Wcat_l, nullptr, nullptr, b_cat, hin, nullptr, N, 1);

    // ---- GAT layer 1 ----
    gemm_mfma<<<dim3(gGrid, 2), 256, 0, stream>>>(
        hin, HBLK, HBLK, nullptr, 0, HBLK, HBLK,
        Wly_h[0], Wly_l[0], Wly_h[1], Wly_l[1], nullptr, hs, zb, N, 0);
    compute_s<<<(N + 3) / 4, 256, 0, stream>>>(zb, a1, ssrc, sdst, N);
    gat_agg<<<N, 128, 0, stream>>>(hin, hs, zb, ssrc, sdst, offs, srcs, hout);

    // ---- GAT layer 2 ----
    gemm_mfma<<<dim3(gGrid, 2), 256, 0, stream>>>(
        hout, HBLK, HBLK, nullptr, 0, HBLK, HBLK,
        Wly_h[2], Wly_l[2], Wly_h[3], Wly_l[3], nullptr, hs, zb, N, 0);
    compute_s<<<(N + 3) / 4, 256, 0, stream>>>(zb, a2, ssrc, sdst, N);
    gat_agg<<<N, 128, 0, stream>>>(hout, hs, zb, ssrc, sdst, offs, srcs, hin);

    // ---- output projection ----
    out_proj<<<N, 128, 0, stream>>>(hin, W_out, b_out, (float*)d_out, OUTD);
}

// Round 6
// 440.692 us; speedup vs baseline: 1.4603x; 1.1084x over previous
//
#include <hip/hip_runtime.h>

#define HBLK 128  // hidden width, fixed by problem

typedef __attribute__((ext_vector_type(8))) short s8v;    // 8 bf16 in 4 VGPRs
typedef __attribute__((ext_vector_type(4))) float f32x4;  // MFMA accumulator

// split fp32 into bf16 hi + lo (truncation; residual <= 2^-16 |x|)
__device__ inline void split2(float x, short& h, short& l) {
    unsigned hb = __float_as_uint(x) & 0xFFFF0000u;
    float hf = __uint_as_float(hb);
    float lf = x - hf;
    h = (short)(hb >> 16);
    l = (short)(__float_as_uint(lf) >> 16);
}

// ---------------- CSR build ----------------
__global__ void zero_counts(int* counts, int n) {
    int i = blockIdx.x * 256 + threadIdx.x;
    if (i < n) counts[i] = 0;
}

__global__ void hist_k(const int* __restrict__ dst, int* counts, int E) {
    int e = blockIdx.x * 256 + threadIdx.x;
    if (e < E) atomicAdd(&counts[dst[e]], 1);
}

// ---- parallel exclusive scan, 3 phases (N up to 256*256) ----
__global__ void scan1(const int* __restrict__ counts, int* __restrict__ offs,
                      int* __restrict__ bsums, int n) {
    __shared__ int lds[256];
    const int t = threadIdx.x;
    const int i = blockIdx.x * 256 + t;
    const int v = (i < n) ? counts[i] : 0;
    lds[t] = v;
    __syncthreads();
    for (int off = 1; off < 256; off <<= 1) {
        int add = (t >= off) ? lds[t - off] : 0;
        __syncthreads();
        lds[t] += add;
        __syncthreads();
    }
    if (i < n) offs[i] = lds[t] - v;          // exclusive within block
    if (t == 255) bsums[blockIdx.x] = lds[255];
}

__global__ void scan2(int* __restrict__ bsums, int nb) {
    __shared__ int lds[256];
    const int t = threadIdx.x;
    const int v = (t < nb) ? bsums[t] : 0;
    lds[t] = v;
    __syncthreads();
    for (int off = 1; off < 256; off <<= 1) {
        int add = (t >= off) ? lds[t - off] : 0;
        __syncthreads();
        lds[t] += add;
        __syncthreads();
    }
    if (t < nb) bsums[t] = lds[t] - v;        // exclusive block prefix
}

__global__ void scan3(int* __restrict__ offs, int* __restrict__ cursor,
                      const int* __restrict__ bsums, int n, int E) {
    const int i = blockIdx.x * 256 + threadIdx.x;
    if (i < n) {
        int v = offs[i] + bsums[blockIdx.x];
        offs[i] = v;
        cursor[i] = v;
    }
    if (i == 0) offs[n] = E;                  // total: every edge has a dst
}

__global__ void fill_k(const int* __restrict__ dst, const int* __restrict__ src,
                       int* cursor, int* __restrict__ src_sorted, int E) {
    int e = blockIdx.x * 256 + threadIdx.x;
    if (e < E) {
        int p = atomicAdd(&cursor[dst[e]], 1);
        src_sorted[p] = src[e];
    }
}

// ---------------- weight split + pack into MFMA-fragment order ----------------
// W: [C=128 rows][kin cols] fp32 row-major -> dh/dl packed so a wave's fragment
// load for (chunk=k/32, j=c/16) is contiguous: off = ((chunk*8+j)*64 + lane)*8 + t
// where lane = quad*16 + l16, c = j*16+l16, k = chunk*32 + quad*8 + t. K padded w/ 0.
__global__ void split_w_pack(const float* __restrict__ W, int ldw, int kin,
                             short* __restrict__ dh, short* __restrict__ dl,
                             int C, int K) {
    long i = (long)blockIdx.x * 256 + threadIdx.x;
    if (i >= (long)C * K) return;
    int c = (int)(i / K), k = (int)(i % K);
    float x = (k < kin) ? W[(long)c * ldw + k] : 0.f;
    short h, l;
    split2(x, h, l);
    int j = c >> 4, l16 = c & 15;
    int chunk = k >> 5, quad = (k >> 3) & 3, t = k & 7;
    long off = (((long)(chunk * 8 + j) * 64) + quad * 16 + l16) * 8 + t;
    dh[off] = h;
    dl[off] = l;
}

// ---------------- split-fp32 MFMA GEMM, software-pipelined, no LDS ----------------
// C[M x 128] = act([A1|A2] @ W^T + bias); A fp32 row-major (split to bf16 hi/lo
// in-register), W pre-split+packed. Emulation: ah*wh + ah*wl + al*wh.
// K1 and Kin multiples of 8; K (padded) multiple of 64. blockIdx.y picks W1/C1 vs W2/C2.
__global__ __launch_bounds__(256, 2) void gemm_mfma(
    const float* __restrict__ A1, int lda1, int K1,
    const float* __restrict__ A2, int lda2, int Kin,
    int K,
    const short* __restrict__ W1h, const short* __restrict__ W1l,
    const short* __restrict__ W2h, const short* __restrict__ W2l,
    const float* __restrict__ bias,
    float* __restrict__ C1f, float* __restrict__ C2f,
    int M, int relu)
{
    const short* __restrict__ Wh = blockIdx.y ? W2h : W1h;
    const short* __restrict__ Wl = blockIdx.y ? W2l : W1l;
    float* __restrict__ Cf = blockIdx.y ? C2f : C1f;
    const int wv = threadIdx.x >> 6;
    const int lane = threadIdx.x & 63;
    const int l16 = lane & 15;
    const int quad = lane >> 4;
    const int m0 = blockIdx.x * 64 + wv * 16;   // this wave's 16-row tile
    int ra = m0 + l16;
    if (ra >= M) ra = M - 1;                    // clamp loads; stores guarded
    const long r1 = (long)ra * lda1;
    const long r2 = (long)ra * lda2;

    f32x4 acc[8];
#pragma unroll
    for (int j = 0; j < 8; ++j) acc[j] = (f32x4){0.f, 0.f, 0.f, 0.f};

    // raw A loads (fp32) for one chunk: 8 floats at col0 = kb + quad*8
#define LOAD_A_RAW(dst0, dst1, kb)                                              \
    {                                                                           \
        const int col0 = (kb) + quad * 8;                                       \
        if (col0 < K1) {                                                        \
            const float* ap = A1 + r1 + col0;                                   \
            dst0 = *(const float4*)ap;                                          \
            dst1 = *(const float4*)(ap + 4);                                    \
        } else if (col0 < Kin) {                                                \
            const float* ap = A2 + r2 + (col0 - K1);                            \
            dst0 = *(const float4*)ap;                                          \
            dst1 = *(const float4*)(ap + 4);                                    \
        } else {                                                                \
            dst0 = make_float4(0.f, 0.f, 0.f, 0.f);                             \
            dst1 = make_float4(0.f, 0.f, 0.f, 0.f);                             \
        }                                                                       \
    }

#define LOAD_W(wharr, wlarr, kb)                                                \
    {                                                                           \
        const long cb = (long)((kb) >> 5) * 4096 + (long)lane * 8;              \
        _Pragma("unroll")                                                       \
        for (int j = 0; j < 8; ++j) {                                           \
            wharr[j] = *(const s8v*)(Wh + cb + j * 512);                        \
            wlarr[j] = *(const s8v*)(Wl + cb + j * 512);                        \
        }                                                                       \
    }

#define SPLIT_A(a0, a1, ah, al)                                                 \
    {                                                                           \
        float vv[8];                                                            \
        *(float4*)&vv[0] = a0;                                                  \
        *(float4*)&vv[4] = a1;                                                  \
        _Pragma("unroll")                                                       \
        for (int e = 0; e < 8; ++e) {                                           \
            short hh, ll;                                                       \
            split2(vv[e], hh, ll);                                              \
            ah[e] = hh;                                                         \
            al[e] = ll;                                                         \
        }                                                                       \
    }

#define DO_MFMA(ah, al, wharr, wlarr)                                           \
    {                                                                           \
        _Pragma("unroll")                                                       \
        for (int j = 0; j < 8; ++j) {                                           \
            acc[j] = __builtin_amdgcn_mfma_f32_16x16x32_bf16(ah, wharr[j], acc[j], 0, 0, 0); \
            acc[j] = __builtin_amdgcn_mfma_f32_16x16x32_bf16(ah, wlarr[j], acc[j], 0, 0, 0); \
            acc[j] = __builtin_amdgcn_mfma_f32_16x16x32_bf16(al, wharr[j], acc[j], 0, 0, 0); \
        }                                                                       \
    }

    float4 a0r0, a0r1, a1r0, a1r1;
    s8v wh0[8], wl0[8], wh1[8], wl1[8];
    s8v ah, al;

    // preload chunk 0
    LOAD_A_RAW(a0r0, a0r1, 0)
    LOAD_W(wh0, wl0, 0)

    for (int kb = 0; kb < K; kb += 64) {
        // prefetch chunk kb+32 (always exists: K % 64 == 0)
        LOAD_A_RAW(a1r0, a1r1, kb + 32)
        LOAD_W(wh1, wl1, kb + 32)
        // compute chunk kb
        SPLIT_A(a0r0, a0r1, ah, al)
        DO_MFMA(ah, al, wh0, wl0)
        // prefetch chunk kb+64 (or harmless reload of 0 on last iter)
        const int kn = (kb + 64 < K) ? kb + 64 : 0;
        LOAD_A_RAW(a0r0, a0r1, kn)
        LOAD_W(wh0, wl0, kn)
        // compute chunk kb+32
        SPLIT_A(a1r0, a1r1, ah, al)
        DO_MFMA(ah, al, wh1, wl1)
    }

    // C/D layout: col = lane&15, row = quad*4 + reg  (verified m89/m91)
#pragma unroll
    for (int r = 0; r < 4; ++r) {
        const int gr = m0 + quad * 4 + r;
        if (gr >= M) continue;
#pragma unroll
        for (int j = 0; j < 8; ++j) {
            const int col = j * 16 + l16;
            float v = acc[j][r];
            if (bias) v += bias[col];
            if (relu) v = fmaxf(v, 0.f);
            Cf[(long)gr * HBLK + col] = v;
        }
    }
#undef LOAD_A_RAW
#undef LOAD_W
#undef SPLIT_A
#undef DO_MFMA
}

// ---------------- per-node attention-score halves: s_src = z@a[:128], s_dst = z@a[128:] ----------------
__global__ void compute_s(const float* __restrict__ z, const float* __restrict__ a,
                          float* __restrict__ s_src, float* __restrict__ s_dst, int N) {
    const int wave = threadIdx.x >> 6;
    const int lane = threadIdx.x & 63;
    const int n = blockIdx.x * 4 + wave;
    if (n >= N) return;
    const float* zr = z + (long)n * HBLK;
    float v0 = zr[lane], v1 = zr[lane + 64];
    float ss = v0 * a[lane] + v1 * a[lane + 64];
    float sd = v0 * a[128 + lane] + v1 * a[192 + lane];
#pragma unroll
    for (int off = 32; off > 0; off >>= 1) {
        ss += __shfl_down(ss, off);
        sd += __shfl_down(sd, off);
    }
    if (lane == 0) {
        s_src[n] = ss;
        s_dst[n] = sd;
    }
}

// ---------------- GAT edge softmax + aggregation; one block (128 thr) per dst node ----------------
__global__ void gat_agg(const float* __restrict__ h_in, const float* __restrict__ hs,
                        const float* __restrict__ z,
                        const float* __restrict__ s_src, const float* __restrict__ s_dst,
                        const int* __restrict__ offs, const int* __restrict__ src_sorted,
                        float* __restrict__ h_out) {
    const int n = blockIdx.x;
    const int t = threadIdx.x;  // 128
    const int beg = offs[n], end = offs[n + 1];
    const int deg = end - beg;
    const float hin = h_in[(long)n * HBLK + t];
    if (deg == 0) {  // DGL leaves h at h_in; residual doubles it
        h_out[(long)n * HBLK + t] = 2.f * hin;
        return;
    }
    const float sd = s_dst[n];
    __shared__ float red_m[128];
    __shared__ float red_s[128];

    // online-softmax sweep
    float m = -INFINITY, ssum = 0.f;
    for (int i = beg + t; i < end; i += 128) {
        float e = sd + s_src[src_sorted[i]];
        e = e > 0.f ? e : 0.01f * e;
        float nm = fmaxf(m, e);
        ssum = ssum * __expf(m - nm) + __expf(e - nm);
        m = nm;
    }
    red_m[t] = m;
    red_s[t] = ssum;
    __syncthreads();
    for (int s2 = 64; s2 > 0; s2 >>= 1) {
        if (t < s2) {
            float m1 = red_m[t], m2 = red_m[t + s2];
            float s1 = red_s[t], s2v = red_s[t + s2];
            if (m2 > m1) {
                float tmp = m1; m1 = m2; m2 = tmp;
                float ts = s1; s1 = s2v; s2v = ts;
            }
            red_m[t] = m1;
            red_s[t] = (m1 == -INFINITY) ? 0.f : s1 + s2v * __expf(m2 - m1);
        }
        __syncthreads();
    }
    m = red_m[0];
    const float inv = 1.f / fmaxf(red_s[0], 1e-16f);

    // weighted gather: acc = hs + sum alpha * z[src]; each thread owns one column.
    // unroll by 2 to keep two 512B row-loads in flight
    float acc = hs[(long)n * HBLK + t];
    int i = beg;
    for (; i + 2 <= end; i += 2) {
        int s0 = src_sorted[i], s1 = src_sorted[i + 1];
        float e0 = sd + s_src[s0];
        float e1 = sd + s_src[s1];
        e0 = e0 > 0.f ? e0 : 0.01f * e0;
        e1 = e1 > 0.f ? e1 : 0.01f * e1;
        float z0 = z[(long)s0 * HBLK + t];
        float z1 = z[(long)s1 * HBLK + t];
        acc += __expf(e0 - m) * inv * z0;
        acc += __expf(e1 - m) * inv * z1;
    }
    if (i < end) {
        int s0 = src_sorted[i];
        float e0 = sd + s_src[s0];
        e0 = e0 > 0.f ? e0 : 0.01f * e0;
        acc += __expf(e0 - m) * inv * z[(long)s0 * HBLK + t];
    }
    h_out[(long)n * HBLK + t] = hin + acc;
}

// ---------------- output projection: out[N x OUT] = h @ W_out^T + b ----------------
__global__ void out_proj(const float* __restrict__ h, const float* __restrict__ W,
                         const float* __restrict__ b, float* __restrict__ out, int OUTD) {
    __shared__ float hr[HBLK];
    const int n = blockIdx.x;
    const int t = threadIdx.x;  // 128
    hr[t] = h[(long)n * HBLK + t];
    __syncthreads();
    if (t < OUTD) {
        float acc = b[t];
        const float* wr = W + t * HBLK;
#pragma unroll 4
        for (int k = 0; k < HBLK; ++k) acc += hr[k] * wr[k];
        out[(long)n * OUTD + t] = acc;
    }
}

extern "C" void kernel_launch(void* const* d_in, const int* in_sizes, int n_in,
                              void* d_out, int out_size, void* d_ws, size_t ws_size,
                              hipStream_t stream) {
    const float* feats = (const float*)d_in[0];
    const float* maps  = (const float*)d_in[2];
    const int* src = (const int*)d_in[4];
    const int* dst = (const int*)d_in[5];
    const float* W_eh  = (const float*)d_in[6];
    const float* b_eh  = (const float*)d_in[7];
    const float* W_cat = (const float*)d_in[10];
    const float* b_cat = (const float*)d_in[11];
    const float* Ws1 = (const float*)d_in[12];
    const float* Wf1 = (const float*)d_in[13];
    const float* a1  = (const float*)d_in[14];
    const float* Ws2 = (const float*)d_in[15];
    const float* Wf2 = (const float*)d_in[16];
    const float* a2  = (const float*)d_in[17];
    const float* W_out = (const float*)d_in[18];
    const float* b_out = (const float*)d_in[19];

    const int N = in_sizes[3];            // snorm_n is (N,1)
    const int E = in_sizes[4];
    const int IN_DIM = in_sizes[0] / N;   // 24
    const int MAPD = in_sizes[2] / N;     // 512
    const int OUTD = in_sizes[19];        // 24
    const int KCAT = MAPD + HBLK;         // 640 (multiple of 64)
    const int KIN_PAD = 64;               // 24 padded to pipeline granularity

    // ---- workspace layout ----
    char* p = (char*)d_ws;
    const size_t NH = (size_t)N * HBLK;
    float* hin  = (float*)p;  p += NH * 4;
    float* h0   = (float*)p;  p += NH * 4;
    float* hs   = (float*)p;  p += NH * 4;
    float* zb   = (float*)p;  p += NH * 4;
    float* hout = (float*)p;  p += NH * 4;
    float* ssrc = (float*)p;  p += (size_t)N * 4;
    float* sdst = (float*)p;  p += (size_t)N * 4;
    int* counts = (int*)p;    p += (size_t)N * 4;
    int* cursor = (int*)p;    p += (size_t)N * 4;
    int* offs   = (int*)p;    p += (size_t)(N + 1) * 4;
    int* srcs   = (int*)p;    p += (size_t)E * 4;
    int* bsums  = (int*)p;    p += 256 * 4;
    p = (char*)(((uintptr_t)p + 15) & ~(uintptr_t)15);
    short* Weh_h  = (short*)p; p += (size_t)HBLK * KIN_PAD * 2;
    short* Weh_l  = (short*)p; p += (size_t)HBLK * KIN_PAD * 2;
    short* Wcat_h = (short*)p; p += (size_t)HBLK * KCAT * 2;
    short* Wcat_l = (short*)p; p += (size_t)HBLK * KCAT * 2;
    short* Wly_h[4]; short* Wly_l[4];
    for (int i = 0; i < 4; ++i) {
        Wly_h[i] = (short*)p;  p += (size_t)HBLK * HBLK * 2;
        Wly_l[i] = (short*)p;  p += (size_t)HBLK * HBLK * 2;
    }

    // ---- CSR by dst (rebuilt every call; ws is poisoned between calls) ----
    const int nScanB = (N + 255) / 256;   // <= 256 for N <= 65536
    zero_counts<<<nScanB, 256, 0, stream>>>(counts, N);
    hist_k<<<(E + 255) / 256, 256, 0, stream>>>(dst, counts, E);
    scan1<<<nScanB, 256, 0, stream>>>(counts, offs, bsums, N);
    scan2<<<1, 256, 0, stream>>>(bsums, nScanB);
    scan3<<<nScanB, 256, 0, stream>>>(offs, cursor, bsums, N, E);
    fill_k<<<(E + 255) / 256, 256, 0, stream>>>(dst, src, cursor, srcs, E);

    // ---- weight split+pack (small) ----
    split_w_pack<<<(HBLK * KIN_PAD + 255) / 256, 256, 0, stream>>>(
        W_eh, IN_DIM, IN_DIM, Weh_h, Weh_l, HBLK, KIN_PAD);
    split_w_pack<<<(HBLK * KCAT + 255) / 256, 256, 0, stream>>>(
        W_cat, KCAT, KCAT, Wcat_h, Wcat_l, HBLK, KCAT);
    {
        const float* Wly[4] = {Ws1, Wf1, Ws2, Wf2};
        for (int i = 0; i < 4; ++i)
            split_w_pack<<<(HBLK * HBLK + 255) / 256, 256, 0, stream>>>(
                Wly[i], HBLK, HBLK, Wly_h[i], Wly_l[i], HBLK, HBLK);
    }

    const int gGrid = (N + 63) / 64;
    // ---- front GEMM: h0 = feats @ W_eh^T + b_eh ----
    gemm_mfma<<<dim3(gGrid, 1), 256, 0, stream>>>(
        feats, IN_DIM, IN_DIM, nullptr, 0, IN_DIM, KIN_PAD,
        Weh_h, Weh_l, nullptr, nullptr, b_eh, h0, nullptr, N, 0);
    // ---- concat GEMM: hin = relu([maps | h0] @ W_cat^T + b_cat) ----
    gemm_mfma<<<dim3(gGrid, 1), 256, 0, stream>>>(
        maps, MAPD, MAPD, h0, HBLK, KCAT, KCAT,
        Wcat_h, Wcat_l, nullptr, nullptr, b_cat, hin, nullptr, N, 1);

    // ---- GAT layer 1 ----
    gemm_mfma<<<dim3(gGrid, 2), 256, 0, stream>>>(
        hin, HBLK, HBLK, nullptr, 0, HBLK, HBLK,
        Wly_h[0], Wly_l[0], Wly_h[1], Wly_l[1], nullptr, hs, zb, N, 0);
    compute_s<<<(N + 3) / 4, 256, 0, stream>>>(zb, a1, ssrc, sdst, N);
    gat_agg<<<N, 128, 0, stream>>>(hin, hs, zb, ssrc, sdst, offs, srcs, hout);

    // ---- GAT layer 2 ----
    gemm_mfma<<<dim3(gGrid, 2), 256, 0, stream>>>(
        hout, HBLK, HBLK, nullptr, 0, HBLK, HBLK,
        Wly_h[2], Wly_l[2], Wly_h[3], Wly_l[3], nullptr, hs, zb, N, 0);
    compute_s<<<(N + 3) / 4, 256, 0, stream>>>(zb, a2, ssrc, sdst, N);
    gat_agg<<<N, 128, 0, stream>>>(hout, hs, zb, ssrc, sdst, offs, srcs, hin);

    // ---- output projection ----
    out_proj<<<N, 128, 0, stream>>>(hin, W_out, b_out, (float*)d_out, OUTD);
}